// Round 10
// baseline (258.794 us; speedup 1.0000x reference)
//
#include <hip/hip_runtime.h>
#include <hip/hip_bf16.h>

#define N_NODES 20000
#define N_EDGES 100000
#define IN_DIM  128
#define HID     64
#define LAT     32
#define EDIM    16
#define TILE_E  128
#define NTILE   ((N_EDGES + TILE_E - 1) / TILE_E)   // 782
#define NBLK_E  256

typedef __attribute__((ext_vector_type(8))) short bf16x8;
typedef __attribute__((ext_vector_type(4))) float f32x4;
typedef __attribute__((ext_vector_type(4))) int   i32x4;

__device__ __forceinline__ short f2bs(float f) {
    __hip_bfloat16 b = __float2bfloat16(f);
    short s;
    __builtin_memcpy(&s, &b, 2);
    return s;
}
__device__ __forceinline__ unsigned pack2(short a, short b) {
    return (unsigned)(unsigned short)a | ((unsigned)(unsigned short)b << 16);
}

// ---------------------------------------------------------------------------
// prep: kwG [64hh][64oo][16d] bf16 (65536)  -- A rows, linear
//       biasT[64oo][64hh]     bf16 (4096)
//       wT   [64][128] bf16 (8192), rootT [64][64] (4096), mlvT [64][64] (4096)
// total 86016 = 336 * 256
// ---------------------------------------------------------------------------
__global__ __launch_bounds__(256) void k_prep(
        const float* __restrict__ kw,     const float* __restrict__ kb,
        const float* __restrict__ lin_w,  const float* __restrict__ root_w,
        const float* __restrict__ mu_w,   const float* __restrict__ lv_w,
        short* __restrict__ kwG,          short* __restrict__ biasT,
        __hip_bfloat16* __restrict__ wT,  __hip_bfloat16* __restrict__ rootT,
        __hip_bfloat16* __restrict__ mlvT) {
    int i = blockIdx.x * 256 + threadIdx.x;
    if (i < 65536) {
        int c = i >> 4, d = i & 15;                 // c = hh*64+oo
        kwG[i] = f2bs(kw[d * (HID * HID) + c]);
    } else if (i < 65536 + 4096) {
        int j = i - 65536;
        int o = j >> 6, hh = j & 63;
        biasT[j] = f2bs(kb[hh * HID + o]);
    } else if (i < 65536 + 4096 + 8192) {
        int j = i - (65536 + 4096);
        int o = j >> 7, d = j & 127;
        wT[j] = __float2bfloat16(lin_w[d * HID + o]);
    } else if (i < 65536 + 4096 + 8192 + 4096) {
        int j = i - (65536 + 4096 + 8192);
        int o = j >> 6, d = j & 63;
        rootT[j] = __float2bfloat16(root_w[d * HID + o]);
    } else {
        int j = i - (65536 + 4096 + 8192 + 4096);
        int o2 = j >> 6, k = j & 63;
        mlvT[j] = __float2bfloat16(o2 < 32 ? mu_w[k * LAT + o2]
                                           : lv_w[k * LAT + (o2 - 32)]);
    }
}

// ---------------------------------------------------------------------------
// CSR 1: degree via global u32 atomics (100K ops, cheap).
// ---------------------------------------------------------------------------
__global__ __launch_bounds__(256) void k_deg(const int* __restrict__ ei,
                                             unsigned* __restrict__ deg) {
    int e = blockIdx.x * 256 + threadIdx.x;
    if (e < N_EDGES) atomicAdd(&deg[ei[N_EDGES + e]], 1u);
}

// ---------------------------------------------------------------------------
// CSR 2: exclusive scan of deg -> rowptr (1 block, register-serial, shfl).
// ---------------------------------------------------------------------------
__global__ __launch_bounds__(1024) void k_scan(const unsigned* __restrict__ deg,
                                               unsigned* __restrict__ rowptr) {
    __shared__ unsigned wsum[16];
    const int t = threadIdx.x, lane = t & 63;
    unsigned v[20];
    unsigned s = 0;
    const int base = t * 20;
#pragma unroll
    for (int i = 0; i < 20; ++i) {
        int idx = base + i;
        v[i] = (idx < N_NODES) ? deg[idx] : 0u;
        s += v[i];
    }
    unsigned ps = s;
    for (int d = 1; d < 64; d <<= 1) {
        unsigned x = __shfl_up(ps, d);
        if (lane >= d) ps += x;
    }
    if (lane == 63) wsum[t >> 6] = ps;
    __syncthreads();
    if (t == 0) {
        unsigned a = 0;
#pragma unroll
        for (int wv = 0; wv < 16; ++wv) { unsigned x = wsum[wv]; wsum[wv] = a; a += x; }
    }
    __syncthreads();
    unsigned run = wsum[t >> 6] + (ps - s);         // exclusive prefix
#pragma unroll
    for (int i = 0; i < 20; ++i) {
        int idx = base + i;
        run += v[i];
        if (idx < N_NODES) rowptr[idx + 1] = run;
    }
    if (t == 0) rowptr[0] = 0u;
}

// ---------------------------------------------------------------------------
// CSR 3: slot assignment. pos[e] = rowptr[dst] + off[dst]++.
// ---------------------------------------------------------------------------
__global__ __launch_bounds__(256) void k_pos(const int* __restrict__ ei,
                                             const unsigned* __restrict__ rowptr,
                                             unsigned* __restrict__ off,
                                             unsigned* __restrict__ pos) {
    int e = blockIdx.x * 256 + threadIdx.x;
    if (e < N_EDGES) {
        int dst = ei[N_EDGES + e];
        unsigned o = atomicAdd(&off[dst], 1u);
        pos[e] = rowptr[dst] + o;
    }
}

// ---------------------------------------------------------------------------
// Kernel A (MFMA): h_bf = bf16(relu(x @ lin_in_w + lin_in_b))
// ---------------------------------------------------------------------------
__global__ __launch_bounds__(256) void k_lin_mfma(
        const float* __restrict__ x, const __hip_bfloat16* __restrict__ wT,
        const float* __restrict__ lin_b, __hip_bfloat16* __restrict__ hb) {
    const int n0   = blockIdx.x * 16;
    const int q    = threadIdx.x >> 6;
    const int lane = threadIdx.x & 63;
    const int col  = lane & 15, grp = lane >> 4;
    const int oo   = q * 16 + col;

    f32x4 acc = {0.f, 0.f, 0.f, 0.f};
    const float* xp = x + (size_t)(n0 + col) * IN_DIM + grp * 8;
    const __hip_bfloat16* bp = wT + (size_t)oo * IN_DIM + grp * 8;
#pragma unroll
    for (int it = 0; it < 4; ++it) {
        float4 xa = *(const float4*)(xp + it * 32);
        float4 xb = *(const float4*)(xp + it * 32 + 4);
        bf16x8 af;
        af[0] = f2bs(xa.x); af[1] = f2bs(xa.y); af[2] = f2bs(xa.z); af[3] = f2bs(xa.w);
        af[4] = f2bs(xb.x); af[5] = f2bs(xb.y); af[6] = f2bs(xb.z); af[7] = f2bs(xb.w);
        bf16x8 bfv = *(const bf16x8*)(bp + it * 32);
        acc = __builtin_amdgcn_mfma_f32_16x16x32_bf16(af, bfv, acc, 0, 0, 0);
    }
    const float bias = lin_b[oo];
#pragma unroll
    for (int j = 0; j < 4; ++j) {
        int row = grp * 4 + j;
        hb[(size_t)(n0 + row) * HID + oo] =
            __float2bfloat16(fmaxf(acc[j] + bias, 0.f));
    }
}

// ---------------------------------------------------------------------------
// Kernel B (MFMA, persistent LDS weights): edge-MLP + message, direct-slot
// write (no atomics). 256 blocks x 512 thr; full kw table (128KB, swizzled)
// + bf16 h-tile + pos in 150KB LDS. Grid-stride over 782 tiles of 128 edges.
// Wave = (q = oo quarter, egp = edge half). Per hh: 1 swizzled ds_read_b128
// of the A row (k<16 = kw; bias at k16 from biasT regs via grp2 insert),
// 4 MFMAs (edge groups) reuse it. B = edge_attr, b[k16]=1.0.
// D: row = grp*4+j = oo, col = lane&15 = edge. Epilogue: msg += relu(w)*h.
// Output row written at CSR slot pos[e] -> k_out gathers contiguously.
// ---------------------------------------------------------------------------
__global__ __launch_bounds__(512) void k_edge(
        const int* __restrict__ ei, const float* __restrict__ ea,
        const __hip_bfloat16* __restrict__ hb, const short* __restrict__ kwG,
        const short* __restrict__ biasT, const unsigned* __restrict__ pos,
        __hip_bfloat16* __restrict__ msgb) {
    __shared__ __align__(16) short s_kw[HID * HID * EDIM];      // 131072 B
    __shared__ __align__(16) unsigned short s_h[TILE_E][72];    // 18432 B
    __shared__ unsigned s_pos[TILE_E];                          // 512 B

    const int tid  = threadIdx.x;
    const int lane = tid & 63;
    const int w    = tid >> 6;
    const int q    = w & 3, egp = w >> 2;
    const int col  = lane & 15, grp = lane >> 4;
    const int oo   = q * 16 + col;

    // one-time weight stage (linear global -> XOR-swizzled LDS):
    // 16B unit uo = c*2+half (c = hh*64+oo). Swizzle: flip short-bit3 (byte
    // bit4) with oo bit2 -> A-reads spread uniformly over banks.
    for (int uo = tid; uo < 8192; uo += 512) {
        int didx = (uo * 8) ^ (((uo >> 3) & 1) << 3);
        *(i32x4*)(s_kw + didx) = *(const i32x4*)(kwG + uo * 8);
    }

    // per-lane A base (shorts), swizzle baked in; stride/hh = 1024 shorts
    const int abase = ((oo * EDIM + (grp & 1) * 8) ^ (((oo >> 2) & 1) << 3));

    const f32x4 z4 = {0.f, 0.f, 0.f, 0.f};

    for (int t = blockIdx.x; t < NTILE; t += NBLK_E) {
        const int e0 = t * TILE_E;
        __syncthreads();                   // prev tile's reads done (+kw stage)

        // stage h[src] tile as bf16 (1024 16B units / 512 thr)
        for (int v = tid; v < TILE_E * 8; v += 512) {
            int r = v >> 3, sg = v & 7;
            int e = e0 + r; if (e >= N_EDGES) e = N_EDGES - 1;
            int src = ei[e];
            *(i32x4*)(&s_h[r][sg * 8]) = *(const i32x4*)(
                (const unsigned short*)hb + (size_t)src * HID + sg * 8);
        }
        if (tid < TILE_E) {
            int e = e0 + tid;
            s_pos[tid] = (e < N_EDGES) ? pos[e] : 0u;
        }

        // B fragments: edge_attr of this wave's 4 edge groups; 1.0 at k16
        bf16x8 bfr[4];
#pragma unroll
        for (int g = 0; g < 4; ++g) {
            bf16x8 b = {};
            if (grp < 2) {
                int e = e0 + egp * 64 + g * 16 + col;
                if (e >= N_EDGES) e = N_EDGES - 1;
                const float* ep = ea + (size_t)e * EDIM + grp * 8;
                float4 a0 = *(const float4*)ep;
                float4 a1 = *(const float4*)(ep + 4);
                b[0] = f2bs(a0.x); b[1] = f2bs(a0.y); b[2] = f2bs(a0.z); b[3] = f2bs(a0.w);
                b[4] = f2bs(a1.x); b[5] = f2bs(a1.y); b[6] = f2bs(a1.z); b[7] = f2bs(a1.w);
            } else if (grp == 2) {
                b[0] = (short)0x3F80;      // bf16(1.0) at k=16 -> bias slot
            }
            bfr[g] = b;
        }
        __syncthreads();

        f32x4 msg[4] = {z4, z4, z4, z4};
        int aoff = abase;
#pragma unroll 2
        for (int hc = 0; hc < 8; ++hc) {
            // bias slice for hh = hc*8..+7 (global, L1-hot 8KB table)
            bf16x8 bb = *(const bf16x8*)(biasT + oo * HID + hc * 8);
            uint2 hp0[4], hp1[4];
#pragma unroll
            for (int g = 0; g < 4; ++g) {
                int el = egp * 64 + g * 16 + col;
                hp0[g] = *(const uint2*)&s_h[el][hc * 8];
                hp1[g] = *(const uint2*)&s_h[el][hc * 8 + 4];
            }
#pragma unroll
            for (int u = 0; u < 8; ++u) {
                bf16x8 afr = {};
                if (grp < 2) afr = *(const bf16x8*)(s_kw + aoff);
                if (grp == 2) afr[0] = bb[u];
                aoff += HID * EDIM;        // next hh row block
#pragma unroll
                for (int g = 0; g < 4; ++g) {
                    f32x4 wv = __builtin_amdgcn_mfma_f32_16x16x32_bf16(
                                   afr, bfr[g], z4, 0, 0, 0);
                    f32x4 wr = __builtin_elementwise_max(wv, z4);
                    unsigned hw = (u < 4) ? ((u & 2) ? hp0[g].y : hp0[g].x)
                                          : ((u & 2) ? hp1[g].y : hp1[g].x);
                    unsigned hbits = (u & 1) ? (hw & 0xFFFF0000u) : (hw << 16);
                    float hv = __uint_as_float(hbits);
                    f32x4 hs = {hv, hv, hv, hv};
                    msg[g] += wr * hs;
                }
            }
        }

        // write: lane owns edge el, oo = q*16 + grp*4 + {0..3}; CSR slot
#pragma unroll
        for (int g = 0; g < 4; ++g) {
            int el = egp * 64 + g * 16 + col;
            if (e0 + el < N_EDGES) {
                unsigned slot = s_pos[el];
                uint2 o;
                o.x = pack2(f2bs(msg[g][0]), f2bs(msg[g][1]));
                o.y = pack2(f2bs(msg[g][2]), f2bs(msg[g][3]));
                *(uint2*)((unsigned short*)msgb + (size_t)slot * HID
                          + q * 16 + grp * 4) = o;
            }
        }
    }
}

// ---------------------------------------------------------------------------
// Kernel C (MFMA): contiguous CSR gather + root + heads. Block = 16 nodes.
// ---------------------------------------------------------------------------
__global__ __launch_bounds__(256) void k_out(
        const __hip_bfloat16* __restrict__ hb,
        const __hip_bfloat16* __restrict__ msgb,
        const unsigned* __restrict__ rowptr,
        const __hip_bfloat16* __restrict__ rootT, const float* __restrict__ conv_b,
        const __hip_bfloat16* __restrict__ mlvT,  const float* __restrict__ mu_b,
        const float* __restrict__ lv_b, float* __restrict__ out) {
    __shared__ __align__(16) __hip_bfloat16 s_h2[16][72];
    const int n0   = blockIdx.x * 16;
    const int q    = threadIdx.x >> 6;
    const int lane = threadIdx.x & 63;
    const int col  = lane & 15, grp = lane >> 4;
    const int oo   = q * 16 + col;

    f32x4 acc = {0.f, 0.f, 0.f, 0.f};
    const bf16x8* hp8 = (const bf16x8*)(hb + (size_t)(n0 + col) * HID);
    const __hip_bfloat16* bp = rootT + (size_t)oo * HID + grp * 8;
#pragma unroll
    for (int it = 0; it < 2; ++it) {
        bf16x8 af = hp8[it * 4 + grp];
        bf16x8 bfv = *(const bf16x8*)(bp + it * 32);
        acc = __builtin_amdgcn_mfma_f32_16x16x32_bf16(af, bfv, acc, 0, 0, 0);
    }
    const float cb = conv_b[oo];
#pragma unroll
    for (int j = 0; j < 4; ++j) {
        int row = grp * 4 + j;
        int n = n0 + row;
        unsigned p0 = rowptr[n], p1 = rowptr[n + 1];
        float agg = 0.f;
        for (unsigned p = p0; p < p1; ++p)
            agg += __bfloat162float(msgb[(size_t)p * HID + oo]);
        agg /= fmaxf((float)(p1 - p0), 1.f);
        s_h2[row][oo] = __float2bfloat16(fmaxf(acc[j] + agg + cb, 0.f));
    }
    __syncthreads();

    f32x4 acc2 = {0.f, 0.f, 0.f, 0.f};
    const __hip_bfloat16* b2 = mlvT + (size_t)oo * HID + grp * 8;
#pragma unroll
    for (int it = 0; it < 2; ++it) {
        bf16x8 af = *(const bf16x8*)((const char*)&s_h2[col][0] + it * 64 + grp * 16);
        bf16x8 bfv = *(const bf16x8*)(b2 + it * 32);
        acc2 = __builtin_amdgcn_mfma_f32_16x16x32_bf16(af, bfv, acc2, 0, 0, 0);
    }
    const float bias = (oo < 32) ? mu_b[oo] : lv_b[oo - 32];
    float* obase = (oo < 32) ? (out + oo) : (out + (size_t)N_NODES * LAT + (oo - 32));
#pragma unroll
    for (int j = 0; j < 4; ++j) {
        int n = n0 + grp * 4 + j;
        obase[(size_t)n * LAT] = acc2[j] + bias;
    }
}

// ---------------------------------------------------------------------------
extern "C" void kernel_launch(void* const* d_in, const int* in_sizes, int n_in,
                              void* d_out, int out_size, void* d_ws, size_t ws_size,
                              hipStream_t stream) {
    const float* x      = (const float*)d_in[0];
    const int*   ei     = (const int*)  d_in[1];
    const float* ea     = (const float*)d_in[2];
    const float* lin_w  = (const float*)d_in[3];
    const float* lin_b  = (const float*)d_in[4];
    const float* kw     = (const float*)d_in[5];
    const float* kb     = (const float*)d_in[6];
    const float* root_w = (const float*)d_in[7];
    const float* conv_b = (const float*)d_in[8];
    const float* mu_w   = (const float*)d_in[9];
    const float* mu_b   = (const float*)d_in[10];
    const float* lv_w   = (const float*)d_in[11];
    const float* lv_b   = (const float*)d_in[12];
    float* out = (float*)d_out;

    char* p = (char*)d_ws;
    __hip_bfloat16* hbuf   = (__hip_bfloat16*)p; p += (size_t)N_NODES * HID * 2;  // 2.56MB
    __hip_bfloat16* msgb   = (__hip_bfloat16*)p; p += (size_t)N_EDGES * HID * 2;  // 12.8MB
    unsigned*       deg    = (unsigned*)p;       p += (size_t)N_NODES * 4;
    unsigned*       off    = (unsigned*)p;       p += (size_t)N_NODES * 4;
    unsigned*       rowptr = (unsigned*)p;       p += (size_t)(N_NODES + 1) * 4;
    unsigned*       pos    = (unsigned*)p;       p += (size_t)N_EDGES * 4;
    short*          kwG    = (short*)p;          p += 65536 * 2;
    short*          biasT  = (short*)p;          p += 4096 * 2;
    __hip_bfloat16* wT     = (__hip_bfloat16*)p; p += 8192 * 2;
    __hip_bfloat16* rootT  = (__hip_bfloat16*)p; p += 4096 * 2;
    __hip_bfloat16* mlvT   = (__hip_bfloat16*)p; p += 4096 * 2;

    // zero deg + off (contiguous)
    hipMemsetAsync(deg, 0, (size_t)2 * N_NODES * 4, stream);

    k_prep<<<336, 256, 0, stream>>>(kw, kb, lin_w, root_w, mu_w, lv_w,
                                    kwG, biasT, wT, rootT, mlvT);

    k_deg<<<(N_EDGES + 255) / 256, 256, 0, stream>>>(ei, deg);
    k_scan<<<1, 1024, 0, stream>>>(deg, rowptr);
    k_pos<<<(N_EDGES + 255) / 256, 256, 0, stream>>>(ei, rowptr, off, pos);

    k_lin_mfma<<<N_NODES / 16, 256, 0, stream>>>(x, wT, lin_b, hbuf);

    k_edge<<<NBLK_E, 512, 0, stream>>>(ei, ea, hbuf, kwG, biasT, pos, msgb);

    k_out<<<N_NODES / 16, 256, 0, stream>>>(hbuf, msgb, rowptr, rootT, conv_b,
                                            mlvT, mu_b, lv_b, out);
}

// Round 11
// 116.280 us; speedup vs baseline: 2.2256x; 2.2256x over previous
//
#include <hip/hip_runtime.h>
#include <hip/hip_bf16.h>

#define N_NODES 20000
#define N_EDGES 100000
#define IN_DIM  128
#define HID     64
#define LAT     32
#define EDIM    16

typedef __attribute__((ext_vector_type(8))) short bf16x8;
typedef __attribute__((ext_vector_type(4))) float f32x4;

__device__ __forceinline__ short f2bs(float f) {
    __hip_bfloat16 b = __float2bfloat16(f);
    short s;
    __builtin_memcpy(&s, &b, 2);
    return s;
}

// packed bf16 atomic add: mem[p] += lo, mem[p+1] += hi (device scope)
__device__ __forceinline__ void atom_pk_bf16(__hip_bfloat16* p, float a, float b) {
    union { struct { short lo, hi; } s; unsigned int u; } v;
    v.s.lo = f2bs(a);
    v.s.hi = f2bs(b);
    asm volatile("global_atomic_pk_add_bf16 %0, %1, off"
                 :: "v"((unsigned long long)(uintptr_t)p), "v"(v.u) : "memory");
}

// ---------------------------------------------------------------------------
// Fused prep (r8 layout): kwA [64hh][64oo][24]: 16 kw + 8x bias (MFMA-ready
// A rows, k<16 = weights, k=16..23 = bias replicated). wT/rootT/mlvT as before.
// total = 98304 + 8192 + 4096 + 4096 = 114688 = 448 * 256
// ---------------------------------------------------------------------------
__global__ __launch_bounds__(256) void k_prep(
        const float* __restrict__ kw,     const float* __restrict__ kb,
        const float* __restrict__ lin_w,  const float* __restrict__ root_w,
        const float* __restrict__ mu_w,   const float* __restrict__ lv_w,
        short* __restrict__ kwA,          __hip_bfloat16* __restrict__ wT,
        __hip_bfloat16* __restrict__ rootT, __hip_bfloat16* __restrict__ mlvT) {
    int i = blockIdx.x * 256 + threadIdx.x;
    if (i < 98304) {
        int hh  = i / 1536;
        int rem = i - hh * 1536;
        int oo  = rem / 24;
        int s   = rem - oo * 24;
        int c   = hh * 64 + oo;
        float v = (s < 16) ? kw[s * (HID * HID) + c] : kb[c];
        kwA[i] = f2bs(v);
    } else if (i < 98304 + 8192) {
        int j = i - 98304;
        int o = j >> 7, d = j & 127;
        wT[j] = __float2bfloat16(lin_w[d * HID + o]);
    } else if (i < 98304 + 8192 + 4096) {
        int j = i - (98304 + 8192);
        int o = j >> 6, d = j & 63;
        rootT[j] = __float2bfloat16(root_w[d * HID + o]);
    } else {
        int j = i - (98304 + 8192 + 4096);
        int o2 = j >> 6, k = j & 63;
        mlvT[j] = __float2bfloat16(o2 < 32 ? mu_w[k * LAT + o2]
                                           : lv_w[k * LAT + (o2 - 32)]);
    }
}

// ---------------------------------------------------------------------------
// Kernel A (MFMA): h = relu(x @ lin_in_w + lin_in_b)   (f32 out)
// ---------------------------------------------------------------------------
__global__ __launch_bounds__(256) void k_lin_mfma(
        const float* __restrict__ x, const __hip_bfloat16* __restrict__ wT,
        const float* __restrict__ lin_b, float* __restrict__ h) {
    const int n0   = blockIdx.x * 16;
    const int q    = threadIdx.x >> 6;
    const int lane = threadIdx.x & 63;
    const int col  = lane & 15, grp = lane >> 4;
    const int oo   = q * 16 + col;

    f32x4 acc = {0.f, 0.f, 0.f, 0.f};
    const float* xp = x + (size_t)(n0 + col) * IN_DIM + grp * 8;
    const __hip_bfloat16* bp = wT + (size_t)oo * IN_DIM + grp * 8;
#pragma unroll
    for (int it = 0; it < 4; ++it) {
        float4 xa = *(const float4*)(xp + it * 32);
        float4 xb = *(const float4*)(xp + it * 32 + 4);
        bf16x8 af;
        af[0] = f2bs(xa.x); af[1] = f2bs(xa.y); af[2] = f2bs(xa.z); af[3] = f2bs(xa.w);
        af[4] = f2bs(xb.x); af[5] = f2bs(xb.y); af[6] = f2bs(xb.z); af[7] = f2bs(xb.w);
        bf16x8 bfv = *(const bf16x8*)(bp + it * 32);
        acc = __builtin_amdgcn_mfma_f32_16x16x32_bf16(af, bfv, acc, 0, 0, 0);
    }
    const float bias = lin_b[oo];
#pragma unroll
    for (int j = 0; j < 4; ++j) {
        int row = grp * 4 + j;
        h[(size_t)(n0 + row) * HID + oo] = fmaxf(acc[j] + bias, 0.f);
    }
}

// ---------------------------------------------------------------------------
// Kernel B (MFMA, global weight stream, 4x A-reuse): edge-MLP + message +
// scatter. Block = 256 thr / 4 waves / 64 edges. Wave q owns oo quarter and
// ALL 4 edge-groups: per hh ONE global A-row load (kwA: k<16 = kw, k=16 =
// bias via B=1.0 slot) feeds FOUR MFMAs. h staged in LDS as f32, read as
// float4 per 4 hh (static lane-select). No barriers in the loop, no LDS
// weight staging (L2 stream = 192KB/tile, ~300MB total). 4 loads in flight.
// D: row = grp*4+j = oo, col = lane&15 = edge. Scatter: packed bf16 atomics.
// ---------------------------------------------------------------------------
__global__ __launch_bounds__(256) void k_edge(
        const int* __restrict__ ei, const float* __restrict__ ea,
        const float* __restrict__ h, const short* __restrict__ kwA,
        __hip_bfloat16* __restrict__ num, float* __restrict__ cnt) {
    __shared__ __align__(16) float s_h[64][68];   // 17408 B
    __shared__ int s_dst[64];

    const int e0   = blockIdx.x * 64;
    const int tid  = threadIdx.x;
    const int q    = tid >> 6, lane = tid & 63;
    const int col  = lane & 15, grp = lane >> 4;

    // stage h[src] (64 edges x 64 hh) f32, coalesced; 2-way-bank writes (free)
    for (int i = tid; i < 64 * HID; i += 256) {
        int r = i >> 6, c = i & 63;
        int e = e0 + r; if (e >= N_EDGES) e = N_EDGES - 1;
        int src = ei[e];
        s_h[r][c] = h[(size_t)src * HID + c];
    }
    if (tid < 64) {
        int e = e0 + tid; if (e >= N_EDGES) e = N_EDGES - 1;
        s_dst[tid] = ei[N_EDGES + e];
    }

    // B fragments (fixed): edge_attr of the 4 edge-groups; 1.0 at k=16 (bias)
    bf16x8 bfr[4];
#pragma unroll
    for (int g = 0; g < 4; ++g) {
        bf16x8 b = {};
        if (grp < 2) {
            int e = e0 + g * 16 + col; if (e >= N_EDGES) e = N_EDGES - 1;
            const float* ep = ea + (size_t)e * EDIM + grp * 8;
            float4 a0 = *(const float4*)ep;
            float4 a1 = *(const float4*)(ep + 4);
            b[0] = f2bs(a0.x); b[1] = f2bs(a0.y); b[2] = f2bs(a0.z); b[3] = f2bs(a0.w);
            b[4] = f2bs(a1.x); b[5] = f2bs(a1.y); b[6] = f2bs(a1.z); b[7] = f2bs(a1.w);
        } else if (grp == 2) {
            b[0] = (short)0x3F80;      // bf16(1.0) at k=16 -> bias slot
        }
        bfr[g] = b;
    }

    // per-lane A offset into kwA (shorts): row (oo = q*16+col), k-half asel;
    // stride per hh = 64*24 = 1536 shorts
    const int asel = (grp < 2) ? grp : 2;
    int off = (q * 16 + col) * 24 + asel * 8;

    f32x4 msg[4];
    const f32x4 z4 = {0.f, 0.f, 0.f, 0.f};
#pragma unroll
    for (int g = 0; g < 4; ++g) msg[g] = z4;

    __syncthreads();

#pragma unroll 1
    for (int hc = 0; hc < 16; ++hc) {
        // 4 hh worth of A rows, loads issued together (latency overlap)
        bf16x8 a0 = *(const bf16x8*)(kwA + off);
        bf16x8 a1 = *(const bf16x8*)(kwA + off + 1536);
        bf16x8 a2 = *(const bf16x8*)(kwA + off + 3072);
        bf16x8 a3 = *(const bf16x8*)(kwA + off + 4608);
        off += 6144;

        float4 hv[4];
#pragma unroll
        for (int g = 0; g < 4; ++g)
            hv[g] = *(const float4*)&s_h[g * 16 + col][hc * 4];

#pragma unroll
        for (int u = 0; u < 4; ++u) {
            bf16x8 a = (u == 0) ? a0 : (u == 1) ? a1 : (u == 2) ? a2 : a3;
#pragma unroll
            for (int g = 0; g < 4; ++g) {
                f32x4 w = __builtin_amdgcn_mfma_f32_16x16x32_bf16(a, bfr[g],
                                                                  z4, 0, 0, 0);
                f32x4 wr = __builtin_elementwise_max(w, z4);
                const float hs = (u == 0) ? hv[g].x : (u == 1) ? hv[g].y
                               : (u == 2) ? hv[g].z : hv[g].w;
                const f32x4 hsv = {hs, hs, hs, hs};
                msg[g] += wr * hsv;
            }
        }
    }

    // scatter: lane owns edge g*16+col, oo = q*16 + grp*4 + {0..3}
#pragma unroll
    for (int g = 0; g < 4; ++g) {
        if (e0 + g * 16 < N_EDGES) {
            int dst = s_dst[g * 16 + col];
            __hip_bfloat16* base = num + (size_t)dst * HID + q * 16 + grp * 4;
            atom_pk_bf16(base,     msg[g][0], msg[g][1]);
            atom_pk_bf16(base + 2, msg[g][2], msg[g][3]);
        }
    }
    if (tid < 64 && e0 + tid < N_EDGES)
        atomicAdd(cnt + s_dst[tid], 1.f);
}

// ---------------------------------------------------------------------------
// Kernel C (MFMA): agg/root/heads fused. Block = 16 nodes.
// ---------------------------------------------------------------------------
__global__ __launch_bounds__(256) void k_out(
        const float* __restrict__ h, const __hip_bfloat16* __restrict__ numb,
        const float* __restrict__ cnt,
        const __hip_bfloat16* __restrict__ rootT, const float* __restrict__ conv_b,
        const __hip_bfloat16* __restrict__ mlvT,  const float* __restrict__ mu_b,
        const float* __restrict__ lv_b, float* __restrict__ out) {
    __shared__ __align__(16) __hip_bfloat16 s_h2[16][72];
    const int n0   = blockIdx.x * 16;
    const int q    = threadIdx.x >> 6;
    const int lane = threadIdx.x & 63;
    const int col  = lane & 15, grp = lane >> 4;
    const int oo   = q * 16 + col;

    f32x4 acc = {0.f, 0.f, 0.f, 0.f};
    const float* hp = h + (size_t)(n0 + col) * HID + grp * 8;
    const __hip_bfloat16* bp = rootT + (size_t)oo * HID + grp * 8;
#pragma unroll
    for (int it = 0; it < 2; ++it) {
        float4 xa = *(const float4*)(hp + it * 32);
        float4 xb = *(const float4*)(hp + it * 32 + 4);
        bf16x8 af;
        af[0] = f2bs(xa.x); af[1] = f2bs(xa.y); af[2] = f2bs(xa.z); af[3] = f2bs(xa.w);
        af[4] = f2bs(xb.x); af[5] = f2bs(xb.y); af[6] = f2bs(xb.z); af[7] = f2bs(xb.w);
        bf16x8 bfv = *(const bf16x8*)(bp + it * 32);
        acc = __builtin_amdgcn_mfma_f32_16x16x32_bf16(af, bfv, acc, 0, 0, 0);
    }
    const float cb = conv_b[oo];
#pragma unroll
    for (int j = 0; j < 4; ++j) {
        int row = grp * 4 + j;
        int n = n0 + row;
        float agg = __bfloat162float(numb[(size_t)n * HID + oo])
                    / fmaxf(cnt[n], 1.f);
        s_h2[row][oo] = __float2bfloat16(fmaxf(acc[j] + agg + cb, 0.f));
    }
    __syncthreads();

    f32x4 acc2 = {0.f, 0.f, 0.f, 0.f};
    const __hip_bfloat16* b2 = mlvT + (size_t)oo * HID + grp * 8;
#pragma unroll
    for (int it = 0; it < 2; ++it) {
        bf16x8 af = *(const bf16x8*)((const char*)&s_h2[col][0] + it * 64 + grp * 16);
        bf16x8 bfv = *(const bf16x8*)(b2 + it * 32);
        acc2 = __builtin_amdgcn_mfma_f32_16x16x32_bf16(af, bfv, acc2, 0, 0, 0);
    }
    const float bias = (oo < 32) ? mu_b[oo] : lv_b[oo - 32];
    float* obase = (oo < 32) ? (out + oo) : (out + (size_t)N_NODES * LAT + (oo - 32));
#pragma unroll
    for (int j = 0; j < 4; ++j) {
        int n = n0 + grp * 4 + j;
        obase[(size_t)n * LAT] = acc2[j] + bias;
    }
}

// ---------------------------------------------------------------------------
extern "C" void kernel_launch(void* const* d_in, const int* in_sizes, int n_in,
                              void* d_out, int out_size, void* d_ws, size_t ws_size,
                              hipStream_t stream) {
    const float* x      = (const float*)d_in[0];
    const int*   ei     = (const int*)  d_in[1];
    const float* ea     = (const float*)d_in[2];
    const float* lin_w  = (const float*)d_in[3];
    const float* lin_b  = (const float*)d_in[4];
    const float* kw     = (const float*)d_in[5];
    const float* kb     = (const float*)d_in[6];
    const float* root_w = (const float*)d_in[7];
    const float* conv_b = (const float*)d_in[8];
    const float* mu_w   = (const float*)d_in[9];
    const float* mu_b   = (const float*)d_in[10];
    const float* lv_w   = (const float*)d_in[11];
    const float* lv_b   = (const float*)d_in[12];
    float* out = (float*)d_out;

    float* h   = (float*)d_ws;                               // N*64 f32
    float* cnt = h + (size_t)N_NODES * HID;                  // N f32
    __hip_bfloat16* numb = (__hip_bfloat16*)(cnt + N_NODES); // N*64 bf16
    short* kwA = (short*)(numb + (size_t)N_NODES * HID);     // 98304 shorts
    __hip_bfloat16* wT    = (__hip_bfloat16*)(kwA + 98304);  // 8192
    __hip_bfloat16* rootT = wT + 8192;                       // 4096
    __hip_bfloat16* mlvT  = rootT + 4096;                    // 4096

    // zero cnt (f32) + numb (bf16) in one contiguous memset
    hipMemsetAsync(cnt, 0,
                   (size_t)N_NODES * sizeof(float) +
                   (size_t)N_NODES * HID * sizeof(__hip_bfloat16), stream);

    k_prep<<<448, 256, 0, stream>>>(kw, kb, lin_w, root_w, mu_w, lv_w,
                                    kwA, wT, rootT, mlvT);

    k_lin_mfma<<<N_NODES / 16, 256, 0, stream>>>(x, wT, lin_b, h);

    k_edge<<<(N_EDGES + 63) / 64, 256, 0, stream>>>(ei, ea, h, kwA, numb, cnt);

    k_out<<<N_NODES / 16, 256, 0, stream>>>(h, numb, cnt, rootT, conv_b,
                                            mlvT, mu_b, lv_b, out);
}

// Round 12
// 108.716 us; speedup vs baseline: 2.3805x; 1.0696x over previous
//
#include <hip/hip_runtime.h>
#include <hip/hip_bf16.h>

#define N_NODES 20000
#define N_EDGES 100000
#define IN_DIM  128
#define HID     64
#define LAT     32
#define EDIM    16

typedef __attribute__((ext_vector_type(8))) short bf16x8;
typedef __attribute__((ext_vector_type(4))) float f32x4;

__device__ __forceinline__ short f2bs(float f) {
    __hip_bfloat16 b = __float2bfloat16(f);
    short s;
    __builtin_memcpy(&s, &b, 2);
    return s;
}

// packed bf16 atomic add: mem[p] += lo, mem[p+1] += hi (device scope)
__device__ __forceinline__ void atom_pk_bf16(__hip_bfloat16* p, float a, float b) {
    union { struct { short lo, hi; } s; unsigned int u; } v;
    v.s.lo = f2bs(a);
    v.s.hi = f2bs(b);
    asm volatile("global_atomic_pk_add_bf16 %0, %1, off"
                 :: "v"((unsigned long long)(uintptr_t)p), "v"(v.u) : "memory");
}

// relu + weighted accumulate, pinned emission: 4x v_max_f32 + 4x v_fmac_f32.
// m[j] += max(w[j],0) * hs
__device__ __forceinline__ void epi(f32x4 w, float hs, f32x4& m) {
    float w0 = w[0], w1 = w[1], w2 = w[2], w3 = w[3];
    float m0 = m[0], m1 = m[1], m2 = m[2], m3 = m[3];
    asm volatile(
        "v_max_f32 %0, 0, %0\n\t"
        "v_max_f32 %1, 0, %1\n\t"
        "v_max_f32 %2, 0, %2\n\t"
        "v_max_f32 %3, 0, %3\n\t"
        "v_fmac_f32 %4, %0, %8\n\t"
        "v_fmac_f32 %5, %1, %8\n\t"
        "v_fmac_f32 %6, %2, %8\n\t"
        "v_fmac_f32 %7, %3, %8"
        : "+v"(w0), "+v"(w1), "+v"(w2), "+v"(w3),
          "+v"(m0), "+v"(m1), "+v"(m2), "+v"(m3)
        : "v"(hs));
    m[0] = m0; m[1] = m1; m[2] = m2; m[3] = m3;
}

// ---------------------------------------------------------------------------
// Fused prep (r8 layout): kwA [64hh][64oo][24]: 16 kw + 8x bias (MFMA-ready
// A rows, k<16 = weights, k=16..23 = bias replicated). wT/rootT/mlvT as before.
// ---------------------------------------------------------------------------
__global__ __launch_bounds__(256) void k_prep(
        const float* __restrict__ kw,     const float* __restrict__ kb,
        const float* __restrict__ lin_w,  const float* __restrict__ root_w,
        const float* __restrict__ mu_w,   const float* __restrict__ lv_w,
        short* __restrict__ kwA,          __hip_bfloat16* __restrict__ wT,
        __hip_bfloat16* __restrict__ rootT, __hip_bfloat16* __restrict__ mlvT) {
    int i = blockIdx.x * 256 + threadIdx.x;
    if (i < 98304) {
        int hh  = i / 1536;
        int rem = i - hh * 1536;
        int oo  = rem / 24;
        int s   = rem - oo * 24;
        int c   = hh * 64 + oo;
        float v = (s < 16) ? kw[s * (HID * HID) + c] : kb[c];
        kwA[i] = f2bs(v);
    } else if (i < 98304 + 8192) {
        int j = i - 98304;
        int o = j >> 7, d = j & 127;
        wT[j] = __float2bfloat16(lin_w[d * HID + o]);
    } else if (i < 98304 + 8192 + 4096) {
        int j = i - (98304 + 8192);
        int o = j >> 6, d = j & 63;
        rootT[j] = __float2bfloat16(root_w[d * HID + o]);
    } else {
        int j = i - (98304 + 8192 + 4096);
        int o2 = j >> 6, k = j & 63;
        mlvT[j] = __float2bfloat16(o2 < 32 ? mu_w[k * LAT + o2]
                                           : lv_w[k * LAT + (o2 - 32)]);
    }
}

// ---------------------------------------------------------------------------
// Kernel A (MFMA): h = relu(x @ lin_in_w + lin_in_b)   (f32 out)
// ---------------------------------------------------------------------------
__global__ __launch_bounds__(256) void k_lin_mfma(
        const float* __restrict__ x, const __hip_bfloat16* __restrict__ wT,
        const float* __restrict__ lin_b, float* __restrict__ h) {
    const int n0   = blockIdx.x * 16;
    const int q    = threadIdx.x >> 6;
    const int lane = threadIdx.x & 63;
    const int col  = lane & 15, grp = lane >> 4;
    const int oo   = q * 16 + col;

    f32x4 acc = {0.f, 0.f, 0.f, 0.f};
    const float* xp = x + (size_t)(n0 + col) * IN_DIM + grp * 8;
    const __hip_bfloat16* bp = wT + (size_t)oo * IN_DIM + grp * 8;
#pragma unroll
    for (int it = 0; it < 4; ++it) {
        float4 xa = *(const float4*)(xp + it * 32);
        float4 xb = *(const float4*)(xp + it * 32 + 4);
        bf16x8 af;
        af[0] = f2bs(xa.x); af[1] = f2bs(xa.y); af[2] = f2bs(xa.z); af[3] = f2bs(xa.w);
        af[4] = f2bs(xb.x); af[5] = f2bs(xb.y); af[6] = f2bs(xb.z); af[7] = f2bs(xb.w);
        bf16x8 bfv = *(const bf16x8*)(bp + it * 32);
        acc = __builtin_amdgcn_mfma_f32_16x16x32_bf16(af, bfv, acc, 0, 0, 0);
    }
    const float bias = lin_b[oo];
#pragma unroll
    for (int j = 0; j < 4; ++j) {
        int row = grp * 4 + j;
        h[(size_t)(n0 + row) * HID + oo] = fmaxf(acc[j] + bias, 0.f);
    }
}

// ---------------------------------------------------------------------------
// Kernel B (MFMA, global weight stream, 4x A-reuse, asm epilogue):
// Block = 256 thr / 4 waves / 64 edges. Wave q owns oo quarter; per hh ONE
// global A-row load (kwA: k<16 = kw, k=16 = bias via B-1.0 slot) feeds FOUR
// MFMAs (edge-groups). Loads paired (offset:3072 imm), one offset add / 2hh.
// Epilogue pinned by asm: exactly v_max x4 + v_fmac x4 per MFMA.
// D: row = grp*4+j = oo, col = lane&15 = edge (h is scalar per lane).
// Scatter: packed bf16 atomics.
// ---------------------------------------------------------------------------
__global__ __launch_bounds__(256) void k_edge(
        const int* __restrict__ ei, const float* __restrict__ ea,
        const float* __restrict__ h, const short* __restrict__ kwA,
        __hip_bfloat16* __restrict__ num, float* __restrict__ cnt) {
    __shared__ __align__(16) float s_h[64][68];   // 17408 B
    __shared__ int s_dst[64];

    const int e0   = blockIdx.x * 64;
    const int tid  = threadIdx.x;
    const int q    = tid >> 6, lane = tid & 63;
    const int col  = lane & 15, grp = lane >> 4;

    // stage h[src] (64 edges x 64 hh) f32, coalesced
    for (int i = tid; i < 64 * HID; i += 256) {
        int r = i >> 6, c = i & 63;
        int e = e0 + r; if (e >= N_EDGES) e = N_EDGES - 1;
        int src = ei[e];
        s_h[r][c] = h[(size_t)src * HID + c];
    }
    if (tid < 64) {
        int e = e0 + tid; if (e >= N_EDGES) e = N_EDGES - 1;
        s_dst[tid] = ei[N_EDGES + e];
    }

    // B fragments (fixed): edge_attr of the 4 edge-groups; 1.0 at k=16 (bias)
    bf16x8 bfr[4];
#pragma unroll
    for (int g = 0; g < 4; ++g) {
        bf16x8 b = {};
        if (grp < 2) {
            int e = e0 + g * 16 + col; if (e >= N_EDGES) e = N_EDGES - 1;
            const float* ep = ea + (size_t)e * EDIM + grp * 8;
            float4 a0 = *(const float4*)ep;
            float4 a1 = *(const float4*)(ep + 4);
            b[0] = f2bs(a0.x); b[1] = f2bs(a0.y); b[2] = f2bs(a0.z); b[3] = f2bs(a0.w);
            b[4] = f2bs(a1.x); b[5] = f2bs(a1.y); b[6] = f2bs(a1.z); b[7] = f2bs(a1.w);
        } else if (grp == 2) {
            b[0] = (short)0x3F80;      // bf16(1.0) at k=16 -> bias slot
        }
        bfr[g] = b;
    }

    // per-lane A offset into kwA (shorts): row (oo = q*16+col), k-half asel;
    // stride per hh = 64*24 = 1536 shorts (3072 B -> folds as imm offset)
    const int asel = (grp < 2) ? grp : 2;
    int aoff = (q * 16 + col) * 24 + asel * 8;

    f32x4 msg0 = {0.f,0.f,0.f,0.f}, msg1 = msg0, msg2 = msg0, msg3 = msg0;
    const f32x4 z4 = {0.f, 0.f, 0.f, 0.f};

    __syncthreads();

#pragma unroll 2
    for (int hq = 0; hq < 16; ++hq) {            // 4 hh per iter
        float4 hv0 = *(const float4*)&s_h[ 0 + col][hq * 4];
        float4 hv1 = *(const float4*)&s_h[16 + col][hq * 4];
        float4 hv2 = *(const float4*)&s_h[32 + col][hq * 4];
        float4 hv3 = *(const float4*)&s_h[48 + col][hq * 4];
#pragma unroll
        for (int hp = 0; hp < 2; ++hp) {         // 2 hh per iter
            bf16x8 a0 = *(const bf16x8*)(kwA + aoff);
            bf16x8 a1 = *(const bf16x8*)(kwA + aoff + 1536);
            aoff += 3072;
            const float h00 = hp ? hv0.z : hv0.x;
            const float h01 = hp ? hv0.w : hv0.y;
            const float h10 = hp ? hv1.z : hv1.x;
            const float h11 = hp ? hv1.w : hv1.y;
            const float h20 = hp ? hv2.z : hv2.x;
            const float h21 = hp ? hv2.w : hv2.y;
            const float h30 = hp ? hv3.z : hv3.x;
            const float h31 = hp ? hv3.w : hv3.y;

            epi(__builtin_amdgcn_mfma_f32_16x16x32_bf16(a0, bfr[0], z4,0,0,0), h00, msg0);
            epi(__builtin_amdgcn_mfma_f32_16x16x32_bf16(a0, bfr[1], z4,0,0,0), h10, msg1);
            epi(__builtin_amdgcn_mfma_f32_16x16x32_bf16(a0, bfr[2], z4,0,0,0), h20, msg2);
            epi(__builtin_amdgcn_mfma_f32_16x16x32_bf16(a0, bfr[3], z4,0,0,0), h30, msg3);
            epi(__builtin_amdgcn_mfma_f32_16x16x32_bf16(a1, bfr[0], z4,0,0,0), h01, msg0);
            epi(__builtin_amdgcn_mfma_f32_16x16x32_bf16(a1, bfr[1], z4,0,0,0), h11, msg1);
            epi(__builtin_amdgcn_mfma_f32_16x16x32_bf16(a1, bfr[2], z4,0,0,0), h21, msg2);
            epi(__builtin_amdgcn_mfma_f32_16x16x32_bf16(a1, bfr[3], z4,0,0,0), h31, msg3);
        }
    }

    // scatter: lane owns edge g*16+col, oo = q*16 + grp*4 + {0..3}
#pragma unroll
    for (int g = 0; g < 4; ++g) {
        if (e0 + g * 16 < N_EDGES) {
            int dst = s_dst[g * 16 + col];
            __hip_bfloat16* base = num + (size_t)dst * HID + q * 16 + grp * 4;
            const f32x4& m = (g == 0) ? msg0 : (g == 1) ? msg1
                           : (g == 2) ? msg2 : msg3;
            atom_pk_bf16(base,     m[0], m[1]);
            atom_pk_bf16(base + 2, m[2], m[3]);
        }
    }
    if (tid < 64 && e0 + tid < N_EDGES)
        atomicAdd(cnt + s_dst[tid], 1.f);
}

// ---------------------------------------------------------------------------
// Kernel C (MFMA): agg/root/heads fused. Block = 16 nodes.
// ---------------------------------------------------------------------------
__global__ __launch_bounds__(256) void k_out(
        const float* __restrict__ h, const __hip_bfloat16* __restrict__ numb,
        const float* __restrict__ cnt,
        const __hip_bfloat16* __restrict__ rootT, const float* __restrict__ conv_b,
        const __hip_bfloat16* __restrict__ mlvT,  const float* __restrict__ mu_b,
        const float* __restrict__ lv_b, float* __restrict__ out) {
    __shared__ __align__(16) __hip_bfloat16 s_h2[16][72];
    const int n0   = blockIdx.x * 16;
    const int q    = threadIdx.x >> 6;
    const int lane = threadIdx.x & 63;
    const int col  = lane & 15, grp = lane >> 4;
    const int oo   = q * 16 + col;

    f32x4 acc = {0.f, 0.f, 0.f, 0.f};
    const float* hp = h + (size_t)(n0 + col) * HID + grp * 8;
    const __hip_bfloat16* bp = rootT + (size_t)oo * HID + grp * 8;
#pragma unroll
    for (int it = 0; it < 2; ++it) {
        float4 xa = *(const float4*)(hp + it * 32);
        float4 xb = *(const float4*)(hp + it * 32 + 4);
        bf16x8 af;
        af[0] = f2bs(xa.x); af[1] = f2bs(xa.y); af[2] = f2bs(xa.z); af[3] = f2bs(xa.w);
        af[4] = f2bs(xb.x); af[5] = f2bs(xb.y); af[6] = f2bs(xb.z); af[7] = f2bs(xb.w);
        bf16x8 bfv = *(const bf16x8*)(bp + it * 32);
        acc = __builtin_amdgcn_mfma_f32_16x16x32_bf16(af, bfv, acc, 0, 0, 0);
    }
    const float cb = conv_b[oo];
#pragma unroll
    for (int j = 0; j < 4; ++j) {
        int row = grp * 4 + j;
        int n = n0 + row;
        float agg = __bfloat162float(numb[(size_t)n * HID + oo])
                    / fmaxf(cnt[n], 1.f);
        s_h2[row][oo] = __float2bfloat16(fmaxf(acc[j] + agg + cb, 0.f));
    }
    __syncthreads();

    f32x4 acc2 = {0.f, 0.f, 0.f, 0.f};
    const __hip_bfloat16* b2 = mlvT + (size_t)oo * HID + grp * 8;
#pragma unroll
    for (int it = 0; it < 2; ++it) {
        bf16x8 af = *(const bf16x8*)((const char*)&s_h2[col][0] + it * 64 + grp * 16);
        bf16x8 bfv = *(const bf16x8*)(b2 + it * 32);
        acc2 = __builtin_amdgcn_mfma_f32_16x16x32_bf16(af, bfv, acc2, 0, 0, 0);
    }
    const float bias = (oo < 32) ? mu_b[oo] : lv_b[oo - 32];
    float* obase = (oo < 32) ? (out + oo) : (out + (size_t)N_NODES * LAT + (oo - 32));
#pragma unroll
    for (int j = 0; j < 4; ++j) {
        int n = n0 + grp * 4 + j;
        obase[(size_t)n * LAT] = acc2[j] + bias;
    }
}

// ---------------------------------------------------------------------------
extern "C" void kernel_launch(void* const* d_in, const int* in_sizes, int n_in,
                              void* d_out, int out_size, void* d_ws, size_t ws_size,
                              hipStream_t stream) {
    const float* x      = (const float*)d_in[0];
    const int*   ei     = (const int*)  d_in[1];
    const float* ea     = (const float*)d_in[2];
    const float* lin_w  = (const float*)d_in[3];
    const float* lin_b  = (const float*)d_in[4];
    const float* kw     = (const float*)d_in[5];
    const float* kb     = (const float*)d_in[6];
    const float* root_w = (const float*)d_in[7];
    const float* conv_b = (const float*)d_in[8];
    const float* mu_w   = (const float*)d_in[9];
    const float* mu_b   = (const float*)d_in[10];
    const float* lv_w   = (const float*)d_in[11];
    const float* lv_b   = (const float*)d_in[12];
    float* out = (float*)d_out;

    float* h   = (float*)d_ws;                               // N*64 f32
    float* cnt = h + (size_t)N_NODES * HID;                  // N f32
    __hip_bfloat16* numb = (__hip_bfloat16*)(cnt + N_NODES); // N*64 bf16
    short* kwA = (short*)(numb + (size_t)N_NODES * HID);     // 98304 shorts
    __hip_bfloat16* wT    = (__hip_bfloat16*)(kwA + 98304);  // 8192
    __hip_bfloat16* rootT = wT + 8192;                       // 4096
    __hip_bfloat16* mlvT  = rootT + 4096;                    // 4096

    // zero cnt (f32) + numb (bf16) in one contiguous memset
    hipMemsetAsync(cnt, 0,
                   (size_t)N_NODES * sizeof(float) +
                   (size_t)N_NODES * HID * sizeof(__hip_bfloat16), stream);

    k_prep<<<448, 256, 0, stream>>>(kw, kb, lin_w, root_w, mu_w, lv_w,
                                    kwA, wT, rootT, mlvT);

    k_lin_mfma<<<N_NODES / 16, 256, 0, stream>>>(x, wT, lin_b, h);

    k_edge<<<(N_EDGES + 63) / 64, 256, 0, stream>>>(ei, ea, h, kwA, numb, cnt);

    k_out<<<N_NODES / 16, 256, 0, stream>>>(h, numb, cnt, rootT, conv_b,
                                            mlvT, mu_b, lv_b, out);
}